// Round 1
// baseline (104.240 us; speedup 1.0000x reference)
//
#include <hip/hip_runtime.h>

#define BB 8
#define NN 4096
#define CHUNK 512                 // targets per j-chunk (8 KB LDS as float4)
#define RPT 4                     // source rows per thread
#define BLK 256
#define ROWS_PER_BLK (BLK*RPT)    // 1024
#define ROW_TILES (NN/ROWS_PER_BLK) // 4
#define JCH (NN/CHUNK)            // 8
#define TOTAL_ROWS (2*BB*NN)      // 65536 row-minima (both directions)

// ws is re-poisoned to 0xAA before every launch -> must init to +inf each call.
__global__ void cd_init(unsigned int* __restrict__ ws) {
    int i = blockIdx.x * blockDim.x + threadIdx.x;
    ws[i] = 0x7F800000u;  // +inf bits
}

// Per block: one (direction, batch, row-tile, j-chunk). Each thread tracks
// running min over its 4 rows of acc' = 0.5*|t|^2 - <s,t>  (d^2/2 = acc' + 0.5*|s|^2,
// and 0.5*|s|^2 is row-constant so it's added after the min).
__global__ __launch_bounds__(BLK) void cd_min(const float* __restrict__ src,
                                              const float* __restrict__ tgt,
                                              unsigned int* __restrict__ ws) {
    __shared__ float4 tl[CHUNK];
    const int dir = blockIdx.z;
    const float* Sp = dir ? tgt : src;
    const float* Tp = dir ? src : tgt;
    const int b  = blockIdx.y >> 2;   // ROW_TILES == 4
    const int rt = blockIdx.y & 3;
    const int jc = blockIdx.x;
    const int tid = threadIdx.x;

    // Stage j-chunk: (x, y, z, 0.5*|t|^2) per target.
    const float* tb = Tp + ((size_t)b * NN + (size_t)jc * CHUNK) * 3;
    for (int k = tid; k < CHUNK; k += BLK) {
        float x = tb[3*k], y = tb[3*k+1], z = tb[3*k+2];
        tl[k] = make_float4(x, y, z, 0.5f*(x*x + y*y + z*z));
    }
    __syncthreads();

    // Per-thread source rows (strided for coalescing).
    const float* sb = Sp + (size_t)b * NN * 3;
    const int rowBase = rt * ROWS_PER_BLK;
    float nx[RPT], ny[RPT], nz[RPT], q[RPT];
#pragma unroll
    for (int r = 0; r < RPT; ++r) {
        int row = rowBase + r*BLK + tid;
        float x = sb[3*row], y = sb[3*row+1], z = sb[3*row+2];
        nx[r] = -x; ny[r] = -y; nz[r] = -z;
        q[r] = 0.5f*(x*x + y*y + z*z);
    }

    // Two independent min chains per row (break the v_min dependency chain).
    float m0[RPT], m1[RPT];
#pragma unroll
    for (int r = 0; r < RPT; ++r) { m0[r] = 1.0e30f; m1[r] = 1.0e30f; }

    for (int j = 0; j < CHUNK; j += 2) {
        float4 t0 = tl[j];      // wave-uniform address -> LDS broadcast
        float4 t1 = tl[j+1];
#pragma unroll
        for (int r = 0; r < RPT; ++r) {
            float a0 = fmaf(nx[r], t0.x, fmaf(ny[r], t0.y, fmaf(nz[r], t0.z, t0.w)));
            float a1 = fmaf(nx[r], t1.x, fmaf(ny[r], t1.y, fmaf(nz[r], t1.z, t1.w)));
            m0[r] = fminf(m0[r], a0);
            m1[r] = fminf(m1[r], a1);
        }
    }

    unsigned int* wsd = ws + (size_t)dir * (BB*NN) + (size_t)b * NN;
#pragma unroll
    for (int r = 0; r < RPT; ++r) {
        int row = rowBase + r*BLK + tid;
        float v = fminf(m0[r], m1[r]) + q[r];   // = d2_min / 2 over this chunk
        v = fmaxf(v, 0.0f);                     // clamp rounding negatives -> uint order == float order
        atomicMin(&wsd[row], __float_as_uint(v));
    }
}

__global__ __launch_bounds__(1024) void cd_reduce(const unsigned int* __restrict__ ws,
                                                  float* __restrict__ out) {
    __shared__ float part[16];
    float sum = 0.0f;
    for (int i = threadIdx.x; i < TOTAL_ROWS; i += 1024) {
        float v = __uint_as_float(ws[i]);
        sum += sqrtf(2.0f * v);   // dist = sqrt(2 * (d2/2))
    }
#pragma unroll
    for (int o = 32; o > 0; o >>= 1) sum += __shfl_down(sum, o, 64);
    int wave = threadIdx.x >> 6;
    int lane = threadIdx.x & 63;
    if (lane == 0) part[wave] = sum;
    __syncthreads();
    if (threadIdx.x == 0) {
        float t = 0.0f;
#pragma unroll
        for (int w = 0; w < 16; ++w) t += part[w];
        out[0] = t * (1.0f / (float)(BB * NN));  // mean(term1) + mean(term2)
    }
}

extern "C" void kernel_launch(void* const* d_in, const int* in_sizes, int n_in,
                              void* d_out, int out_size, void* d_ws, size_t ws_size,
                              hipStream_t stream) {
    const float* src = (const float*)d_in[0];
    const float* tgt = (const float*)d_in[1];
    unsigned int* ws = (unsigned int*)d_ws;   // needs 65536 * 4 = 256 KB
    float* out = (float*)d_out;

    cd_init<<<TOTAL_ROWS / 256, 256, 0, stream>>>(ws);
    dim3 grid(JCH, BB * ROW_TILES, 2);
    cd_min<<<grid, BLK, 0, stream>>>(src, tgt, ws);
    cd_reduce<<<1, 1024, 0, stream>>>(ws, out);
}

// Round 2
// 80.596 us; speedup vs baseline: 1.2934x; 1.2934x over previous
//
#include <hip/hip_runtime.h>

#define BB 8
#define NN 4096
#define BLK 256
#define RPT 4
#define ROWS 128                  // source rows per block
#define SLICES 8                  // j-slices per block (tid>>5), half-wave uniform
#define JSL (NN/SLICES)           // 512 targets per slice
#define NBLK (2*BB*(NN/ROWS))     // 512 blocks

// Each block owns ROWS source rows for one (dir, batch) and scans ALL NN
// targets (staged once in LDS). No cross-block state -> no ws init, no atomics.
__global__ __launch_bounds__(BLK) void cd_main(const float* __restrict__ src,
                                               const float* __restrict__ tgt,
                                               float* __restrict__ partial) {
    __shared__ float4 tl[NN];                // 64 KB: (x, y, z, 0.5*|t|^2)
    __shared__ float pmin[SLICES * ROWS];    // 4 KB slice-partial mins
    __shared__ float bsum[4];
    const int dir = blockIdx.z;
    const float* Sp = dir ? tgt : src;
    const float* Tp = dir ? src : tgt;
    const int b   = blockIdx.y;
    const int rt  = blockIdx.x;
    const int tid = threadIdx.x;

    // Stage all targets: (x,y,z, 0.5|t|^2). L2-hot (inputs total 786 KB).
    const float* tb = Tp + (size_t)b * NN * 3;
    for (int k = tid; k < NN; k += BLK) {
        float x = tb[3*k], y = tb[3*k+1], z = tb[3*k+2];
        tl[k] = make_float4(x, y, z, 0.5f*(x*x + y*y + z*z));
    }

    // Per-thread source rows (half-wave strided -> coalesced enough, L2-hot).
    const float* sb = Sp + (size_t)b * NN * 3;
    const int sub   = tid & 31;
    const int slice = tid >> 5;
    const int rowBase = rt * ROWS;
    float nx[RPT], ny[RPT], nz[RPT], q[RPT];
#pragma unroll
    for (int r = 0; r < RPT; ++r) {
        int row = rowBase + sub + 32*r;
        float x = sb[3*row], y = sb[3*row+1], z = sb[3*row+2];
        nx[r] = -x; ny[r] = -y; nz[r] = -z;
        q[r] = 0.5f*(x*x + y*y + z*z);
    }
    __syncthreads();

    // min over this slice's j of (0.5|t|^2 - <s,t>); row-constant 0.5|s|^2
    // added after the min. Two chains break the v_min dependency.
    float m0[RPT], m1[RPT];
#pragma unroll
    for (int r = 0; r < RPT; ++r) { m0[r] = 1.0e30f; m1[r] = 1.0e30f; }

    const float4* tp = tl + slice * JSL;
#pragma unroll 2
    for (int j = 0; j < JSL; j += 2) {
        float4 t0 = tp[j];        // half-wave-uniform addr -> 2-way LDS (free)
        float4 t1 = tp[j+1];
#pragma unroll
        for (int r = 0; r < RPT; ++r) {
            float a0 = fmaf(nx[r], t0.x, fmaf(ny[r], t0.y, fmaf(nz[r], t0.z, t0.w)));
            float a1 = fmaf(nx[r], t1.x, fmaf(ny[r], t1.y, fmaf(nz[r], t1.z, t1.w)));
            m0[r] = fminf(m0[r], a0);
            m1[r] = fminf(m1[r], a1);
        }
    }

#pragma unroll
    for (int r = 0; r < RPT; ++r)
        pmin[slice*ROWS + sub + 32*r] = fminf(m0[r], m1[r]) + q[r];
    __syncthreads();

    // Threads 0..127: combine 8 slice-partials per row, then sqrt(2*d2half).
    float dsum = 0.0f;
    if (tid < ROWS) {
        float v = pmin[tid];
#pragma unroll
        for (int s = 1; s < SLICES; ++s) v = fminf(v, pmin[s*ROWS + tid]);
        v = fmaxf(v, 0.0f);
        dsum = sqrtf(2.0f * v);
    }
    // Block sum (inactive threads contribute 0).
#pragma unroll
    for (int o = 32; o > 0; o >>= 1) dsum += __shfl_down(dsum, o, 64);
    if ((tid & 63) == 0) bsum[tid >> 6] = dsum;
    __syncthreads();
    if (tid == 0)
        partial[((size_t)dir*BB + b)*32 + rt] = bsum[0] + bsum[1] + bsum[2] + bsum[3];
}

__global__ __launch_bounds__(512) void cd_final(const float* __restrict__ partial,
                                                float* __restrict__ out) {
    __shared__ float ps[8];
    float v = partial[threadIdx.x];
#pragma unroll
    for (int o = 32; o > 0; o >>= 1) v += __shfl_down(v, o, 64);
    if ((threadIdx.x & 63) == 0) ps[threadIdx.x >> 6] = v;
    __syncthreads();
    if (threadIdx.x == 0) {
        float t = 0.0f;
#pragma unroll
        for (int w = 0; w < 8; ++w) t += ps[w];
        out[0] = t * (1.0f / (float)(BB * NN));   // mean(term1) + mean(term2)
    }
}

extern "C" void kernel_launch(void* const* d_in, const int* in_sizes, int n_in,
                              void* d_out, int out_size, void* d_ws, size_t ws_size,
                              hipStream_t stream) {
    const float* src = (const float*)d_in[0];
    const float* tgt = (const float*)d_in[1];
    float* partial = (float*)d_ws;     // 512 floats, fully overwritten each call
    float* out = (float*)d_out;

    dim3 grid(NN/ROWS, BB, 2);         // 32 x 8 x 2 = 512 blocks
    cd_main<<<grid, BLK, 0, stream>>>(src, tgt, partial);
    cd_final<<<1, 512, 0, stream>>>(partial, out);
}